// Round 11
// baseline (196.908 us; speedup 1.0000x reference)
//
#include <hip/hip_runtime.h>
#include <math.h>

#define N_NODES 50000
#define N_EDGES 800000
#define E_TOT   (N_EDGES + N_NODES)
#define NEG_SLOPE 0.2f
#define NPB      128                       // nodes per bucket
#define NB_BKT  ((N_NODES + NPB - 1) / NPB)   // 391 dst-buckets
#define BKT_CAP 3200                       // mean 2176 + 22 sigma (uniform dst)
#define P1_CHUNK 4096
#define NB_P1   ((E_TOT + P1_CHUNK - 1) / P1_CHUNK)   // 208 scatter blocks
#define NB_G1   ((N_NODES + 127) / 128)    // 391 gemm blocks

typedef short bf16x8 __attribute__((ext_vector_type(8)));
typedef float f32x4 __attribute__((ext_vector_type(4)));

static __device__ __forceinline__ float lrelu(float v) {
    return v > 0.0f ? v : NEG_SLOPE * v;
}

// round-to-nearest-even fp32 -> bf16
static __device__ __forceinline__ unsigned short f2bf(float f) {
    unsigned b = __float_as_uint(f);
    return (unsigned short)((b + 0x7fffu + ((b >> 16) & 1u)) >> 16);
}

static __device__ __forceinline__ float bflo(unsigned u) { return __uint_as_float(u << 16); }
static __device__ __forceinline__ float bfhi(unsigned u) { return __uint_as_float(u & 0xffff0000u); }

// LDS index (ushort units) for element (row, k) of a row*128 bf16 tile.
static __device__ __forceinline__ int swz(int row, int k) {
    return row * 128 + ((((k >> 3) ^ (row & 15)) << 3) | (k & 7));
}
static __device__ __forceinline__ int swz64(int row, int c) {
    return row * 64 + ((((c >> 3) ^ (row & 7)) << 3) | (c & 7));
}

// -------- fused A: blocks [0,NB_G1) = GEMM1 (bf16 MFMA) + alphas1;
//                   blocks [NB_G1, NB_G1+NB_P1) = bucket-binned edge scatter.
__global__ __launch_bounds__(256, 2) void fusedA_kernel(const float* __restrict__ x,
                                                        const float* __restrict__ W,
                                                        const float* __restrict__ a_src,
                                                        const float* __restrict__ a_dst,
                                                        unsigned short* __restrict__ h1b,
                                                        float* __restrict__ as_out,
                                                        float* __restrict__ ad_out,
                                                        const int* __restrict__ ei,
                                                        int* __restrict__ bktcnt,
                                                        uint2* __restrict__ pairs) {
    __shared__ __align__(16) unsigned char smem[65536];
    int tid = threadIdx.x;

    if (blockIdx.x >= NB_G1) {
        // ---------------- scatter P1 path ----------------
        int* cnt  = (int*)smem;                 // NB_BKT ints
        int* base = (int*)(smem + 2048);        // NB_BKT ints
        for (int i = tid; i < NB_BKT; i += 256) cnt[i] = 0;
        __syncthreads();
        int cbase = (blockIdx.x - NB_G1) * P1_CHUNK;
        for (int i = tid; i < P1_CHUNK; i += 256) {
            int e = cbase + i;
            if (e >= E_TOT) break;
            int d = (e < N_EDGES) ? ei[N_EDGES + e] : (e - N_EDGES);
            atomicAdd(&cnt[d >> 7], 1);
        }
        __syncthreads();
        for (int i = tid; i < NB_BKT; i += 256) {
            int c = cnt[i];
            base[i] = c ? (BKT_CAP * i + atomicAdd(&bktcnt[i], c)) : 0;
            cnt[i] = 0;
        }
        __syncthreads();
        for (int i = tid; i < P1_CHUNK; i += 256) {
            int e = cbase + i;
            if (e >= E_TOT) break;
            int s, d;
            if (e < N_EDGES) { s = ei[e]; d = ei[N_EDGES + e]; }
            else { s = d = e - N_EDGES; }
            int bk = d >> 7;
            int p = base[bk] + atomicAdd(&cnt[bk], 1);
            pairs[p] = make_uint2((unsigned)s, (unsigned)d);
        }
        return;
    }

    // ---------------- GEMM1 path ----------------
    unsigned short* xs = (unsigned short*)smem;            // 32 KB
    unsigned short* wt = (unsigned short*)(smem + 32768);  // 32 KB, W^T
    int r0 = blockIdx.x * 128;

    {   // stage W^T
        int n = tid & 127;
        int c0 = (tid >> 7) * 8;
        for (int c = c0; c < c0 + 8; ++c) {
            int kb = c * 8;
            ushort4 lo, hi;
            lo.x = f2bf(W[(kb + 0) * 128 + n]);
            lo.y = f2bf(W[(kb + 1) * 128 + n]);
            lo.z = f2bf(W[(kb + 2) * 128 + n]);
            lo.w = f2bf(W[(kb + 3) * 128 + n]);
            hi.x = f2bf(W[(kb + 4) * 128 + n]);
            hi.y = f2bf(W[(kb + 5) * 128 + n]);
            hi.z = f2bf(W[(kb + 6) * 128 + n]);
            hi.w = f2bf(W[(kb + 7) * 128 + n]);
            int a = swz(n, kb);
            *(ushort4*)&wt[a] = lo;
            *(ushort4*)&wt[a + 4] = hi;
        }
    }
    {   // stage x rows as bf16
        const int maxe = N_NODES * 128 - 4;
#pragma unroll
        for (int i = 0; i < 16384; i += 1024) {
            int e = i + tid * 4;
            int ge = r0 * 128 + e;
            if (ge > maxe) ge = maxe;
            float4 v = *(const float4*)&x[ge];
            ushort4 p;
            p.x = f2bf(v.x); p.y = f2bf(v.y); p.z = f2bf(v.z); p.w = f2bf(v.w);
            *(ushort4*)&xs[swz(e >> 7, e & 127)] = p;
        }
    }
    __syncthreads();

    int wv = tid >> 6, lane = tid & 63, lm = lane & 15, quad = lane >> 4;
    f32x4 acc[2][8];
#pragma unroll
    for (int m = 0; m < 2; ++m)
#pragma unroll
        for (int n = 0; n < 8; ++n) acc[m][n] = (f32x4){0.f, 0.f, 0.f, 0.f};

#pragma unroll
    for (int kc = 0; kc < 4; ++kc) {
        int kb = kc * 32 + quad * 8;
        bf16x8 a0 = *(bf16x8*)&xs[swz(wv * 32 + lm, kb)];
        bf16x8 a1 = *(bf16x8*)&xs[swz(wv * 32 + 16 + lm, kb)];
#pragma unroll
        for (int nt = 0; nt < 8; ++nt) {
            bf16x8 b = *(bf16x8*)&wt[swz(nt * 16 + lm, kb)];
            acc[0][nt] = __builtin_amdgcn_mfma_f32_16x16x32_bf16(a0, b, acc[0][nt], 0, 0, 0);
            acc[1][nt] = __builtin_amdgcn_mfma_f32_16x16x32_bf16(a1, b, acc[1][nt], 0, 0, 0);
        }
    }

    float asv[8], adv[8];
#pragma unroll
    for (int nt = 0; nt < 8; ++nt) {
        asv[nt] = a_src[nt * 16 + lm];
        adv[nt] = a_dst[nt * 16 + lm];
    }
#pragma unroll
    for (int mt = 0; mt < 2; ++mt) {
#pragma unroll
        for (int r = 0; r < 4; ++r) {
            float s0 = 0.f, s1 = 0.f, d0 = 0.f, d1 = 0.f;
#pragma unroll
            for (int nt = 0; nt < 4; ++nt) {
                s0 += acc[mt][nt][r] * asv[nt];
                d0 += acc[mt][nt][r] * adv[nt];
            }
#pragma unroll
            for (int nt = 4; nt < 8; ++nt) {
                s1 += acc[mt][nt][r] * asv[nt];
                d1 += acc[mt][nt][r] * adv[nt];
            }
#pragma unroll
            for (int m = 1; m < 16; m <<= 1) {
                s0 += __shfl_xor(s0, m, 64);
                s1 += __shfl_xor(s1, m, 64);
                d0 += __shfl_xor(d0, m, 64);
                d1 += __shfl_xor(d1, m, 64);
            }
            if (lm == 0) {
                int gr = r0 + wv * 32 + mt * 16 + quad * 4 + r;
                if (gr < N_NODES) {
                    as_out[gr * 2 + 0] = s0;
                    as_out[gr * 2 + 1] = s1;
                    ad_out[gr * 2 + 0] = d0;
                    ad_out[gr * 2 + 1] = d1;
                }
            }
        }
    }

    __syncthreads();
#pragma unroll
    for (int mt = 0; mt < 2; ++mt) {
#pragma unroll
        for (int nt = 0; nt < 8; ++nt) {
#pragma unroll
            for (int r = 0; r < 4; ++r) {
                int lrow = wv * 32 + mt * 16 + quad * 4 + r;
                xs[swz(lrow, nt * 16 + lm)] = f2bf(acc[mt][nt][r]);
            }
        }
    }
    __syncthreads();
    {
        int lrow = tid >> 1;
        int cb = (tid & 1) * 64;
        int gr = r0 + lrow;
        if (gr < N_NODES) {
            unsigned short* dst = h1b + (size_t)gr * 128 + cb;
#pragma unroll
            for (int c = 0; c < 8; ++c)
                *(uint4*)(dst + c * 8) = *(uint4*)&xs[swz(lrow, cb + c * 8)];
        }
    }
}

// -------- fused agg1: per-bucket sort (in LDS) + csr/offsets/deg write + aggregate --------
// Block = 1024 threads = 16 waves, one bucket of 128 nodes. srcs list in LDS (ushort).
__global__ __launch_bounds__(1024) void agg1_kernel(const unsigned short* __restrict__ h1b,
                                                    const float* __restrict__ as1,
                                                    const float* __restrict__ ad1,
                                                    const float* __restrict__ b1,
                                                    const uint2* __restrict__ pairs,
                                                    const int* __restrict__ bktcnt,
                                                    int* __restrict__ offsets,
                                                    int* __restrict__ deg,
                                                    unsigned short* __restrict__ csr_us,
                                                    unsigned short* __restrict__ out1b) {
    __shared__ unsigned short srcs[BKT_CAP];   // 6.25 KB
    __shared__ int cntL[NPB];                  // counts -> cursors -> end offsets
    __shared__ int offL[NPB];                  // inclusive scan -> exclusive starts
    int t = threadIdx.x;
    int b = blockIdx.x;
    int node0 = b * NPB;
    int pbase = b * BKT_CAP;
    int cntE = bktcnt[b];

    if (t < NPB) cntL[t] = 0;
    __syncthreads();
    for (int j = t; j < cntE; j += 1024)
        atomicAdd(&cntL[pairs[pbase + j].y - node0], 1);
    __syncthreads();
    int c = (t < NPB) ? cntL[t] : 0;
    if (t < NPB) offL[t] = c;
    __syncthreads();
#pragma unroll
    for (int off = 1; off < NPB; off <<= 1) {
        int u = (t >= off && t < NPB) ? offL[t - off] : 0;
        __syncthreads();
        if (t < NPB) offL[t] += u;
        __syncthreads();
    }
    int excl = (t < NPB) ? (offL[t] - c) : 0;
    if (t < NPB) {
        int node = node0 + t;
        if (node < N_NODES) {
            offsets[node] = pbase + excl;
            deg[node] = c;
        }
    }
    __syncthreads();
    if (t < NPB) { offL[t] = excl; cntL[t] = excl; }
    __syncthreads();
    for (int j = t; j < cntE; j += 1024) {
        uint2 pr = pairs[pbase + j];
        int p = atomicAdd(&cntL[pr.y - node0], 1);
        srcs[p] = (unsigned short)pr.x;
    }
    __syncthreads();
    // dump sorted csr for agg2 (coalesced ushort stores)
    for (int j = t; j < cntE; j += 1024)
        csr_us[pbase + j] = srcs[j];

    // ---- aggregation: 16 waves x 8 nodes ----
    int wv = t >> 6, lane = t & 63;
    int cl = lane & 31;
    int half = lane >> 5;
    bool head1 = (cl >= 16);
#pragma unroll
    for (int nt = 0; nt < 8; ++nt) {
        int nl = wv * 8 + nt;
        int node = node0 + nl;
        if (node >= N_NODES) continue;
        int jb = offL[nl], je = cntL[nl];     // cntL is end offset after place
        float da0 = ad1[node * 2 + 0], da1 = ad1[node * 2 + 1];
        float a0 = 0.f, a1 = 0.f, a2 = 0.f, a3 = 0.f;
        float psum0 = 0.f, psum1 = 0.f;

        for (int chunk = jb; chunk < je; chunk += 64) {
            int j = chunk + lane;
            int s = 0; float w0 = 0.f, w1 = 0.f;
            if (j < je) {
                s = (int)srcs[j];
                float2 av = *(const float2*)&as1[s * 2];
                w0 = __expf(lrelu(av.x + da0));
                w1 = __expf(lrelu(av.y + da1));
            }
            psum0 += w0; psum1 += w1;
            int cnt = je - chunk; if (cnt > 64) cnt = 64;
            for (int k = 0; k < cnt; k += 8) {
                int k0 = k + half, k1 = k + 2 + half, k2 = k + 4 + half, k3 = k + 6 + half;
                int ss0 = __shfl(s, k0, 64);
                int ss1 = __shfl(s, k1, 64);
                int ss2 = __shfl(s, k2, 64);
                int ss3 = __shfl(s, k3, 64);
                uint2 u0 = ((const uint2*)(h1b + (size_t)ss0 * 128))[cl];
                uint2 u1 = ((const uint2*)(h1b + (size_t)ss1 * 128))[cl];
                uint2 u2 = ((const uint2*)(h1b + (size_t)ss2 * 128))[cl];
                uint2 u3 = ((const uint2*)(h1b + (size_t)ss3 * 128))[cl];
                float p0 = __shfl(w0, k0, 64), q0 = __shfl(w1, k0, 64);
                float p1 = __shfl(w0, k1, 64), q1 = __shfl(w1, k1, 64);
                float p2 = __shfl(w0, k2, 64), q2 = __shfl(w1, k2, 64);
                float p3 = __shfl(w0, k3, 64), q3 = __shfl(w1, k3, 64);
                float bw0 = head1 ? q0 : p0;
                float bw1 = head1 ? q1 : p1;
                float bw2 = head1 ? q2 : p2;
                float bw3 = head1 ? q3 : p3;
                a0 += bw0 * bflo(u0.x); a1 += bw0 * bfhi(u0.x); a2 += bw0 * bflo(u0.y); a3 += bw0 * bfhi(u0.y);
                a0 += bw1 * bflo(u1.x); a1 += bw1 * bfhi(u1.x); a2 += bw1 * bflo(u1.y); a3 += bw1 * bfhi(u1.y);
                a0 += bw2 * bflo(u2.x); a1 += bw2 * bfhi(u2.x); a2 += bw2 * bflo(u2.y); a3 += bw2 * bfhi(u2.y);
                a0 += bw3 * bflo(u3.x); a1 += bw3 * bfhi(u3.x); a2 += bw3 * bflo(u3.y); a3 += bw3 * bfhi(u3.y);
            }
        }
#pragma unroll
        for (int m = 1; m < 64; m <<= 1) {
            psum0 += __shfl_xor(psum0, m, 64);
            psum1 += __shfl_xor(psum1, m, 64);
        }
        float o0 = __shfl(a0, cl + 32, 64);
        float o1 = __shfl(a1, cl + 32, 64);
        float o2 = __shfl(a2, cl + 32, 64);
        float o3 = __shfl(a3, cl + 32, 64);
        if (lane < 32) {
            float inv = 1.f / (head1 ? psum1 : psum0);
            float4 bv = *(const float4*)&b1[cl * 4];
            float v0 = (a0 + o0) * inv + bv.x;
            float v1 = (a1 + o1) * inv + bv.y;
            float v2 = (a2 + o2) * inv + bv.z;
            float v3 = (a3 + o3) * inv + bv.w;
            v0 = v0 > 0.f ? v0 : 0.f;
            v1 = v1 > 0.f ? v1 : 0.f;
            v2 = v2 > 0.f ? v2 : 0.f;
            v3 = v3 > 0.f ? v3 : 0.f;
            ushort4 p;
            p.x = f2bf(v0); p.y = f2bf(v1); p.z = f2bf(v2); p.w = f2bf(v3);
            *(ushort4*)&out1b[(size_t)node * 128 + cl * 4] = p;
        }
    }
}

// -------- GEMM 2 (bf16 MFMA) + fused alphas2: h2b[N,64], as2/ad2[N] --------
__global__ __launch_bounds__(256, 2) void gemm2_kernel(const unsigned short* __restrict__ xb,
                                                       const float* __restrict__ W,
                                                       const float* __restrict__ a_src,
                                                       const float* __restrict__ a_dst,
                                                       unsigned short* __restrict__ h2b,
                                                       float* __restrict__ as_out,
                                                       float* __restrict__ ad_out) {
    __shared__ unsigned short xs[128 * 128];  // 32 KB
    __shared__ unsigned short wt[64 * 128];   // 16 KB, W^T
    int tid = threadIdx.x;
    int r0 = blockIdx.x * 128;

    {
        int n = tid & 63;
        int c0 = (tid >> 6) * 4;
        for (int c = c0; c < c0 + 4; ++c) {
            int kb = c * 8;
            ushort4 lo, hi;
            lo.x = f2bf(W[(kb + 0) * 64 + n]);
            lo.y = f2bf(W[(kb + 1) * 64 + n]);
            lo.z = f2bf(W[(kb + 2) * 64 + n]);
            lo.w = f2bf(W[(kb + 3) * 64 + n]);
            hi.x = f2bf(W[(kb + 4) * 64 + n]);
            hi.y = f2bf(W[(kb + 5) * 64 + n]);
            hi.z = f2bf(W[(kb + 6) * 64 + n]);
            hi.w = f2bf(W[(kb + 7) * 64 + n]);
            int a = swz(n, kb);
            *(ushort4*)&wt[a] = lo;
            *(ushort4*)&wt[a + 4] = hi;
        }
    }
    {
        const int maxe = N_NODES * 128 - 8;
#pragma unroll
        for (int i = 0; i < 16384; i += 2048) {
            int e = i + tid * 8;
            int ge = r0 * 128 + e;
            if (ge > maxe) ge = maxe;
            uint4 v = *(const uint4*)&xb[ge];
            *(uint4*)&xs[swz(e >> 7, e & 127)] = v;
        }
    }
    __syncthreads();

    int wv = tid >> 6, lane = tid & 63, lm = lane & 15, quad = lane >> 4;
    f32x4 acc[2][4];
#pragma unroll
    for (int m = 0; m < 2; ++m)
#pragma unroll
        for (int n = 0; n < 4; ++n) acc[m][n] = (f32x4){0.f, 0.f, 0.f, 0.f};

#pragma unroll
    for (int kc = 0; kc < 4; ++kc) {
        int kb = kc * 32 + quad * 8;
        bf16x8 a0 = *(bf16x8*)&xs[swz(wv * 32 + lm, kb)];
        bf16x8 a1 = *(bf16x8*)&xs[swz(wv * 32 + 16 + lm, kb)];
#pragma unroll
        for (int nt = 0; nt < 4; ++nt) {
            bf16x8 b = *(bf16x8*)&wt[swz(nt * 16 + lm, kb)];
            acc[0][nt] = __builtin_amdgcn_mfma_f32_16x16x32_bf16(a0, b, acc[0][nt], 0, 0, 0);
            acc[1][nt] = __builtin_amdgcn_mfma_f32_16x16x32_bf16(a1, b, acc[1][nt], 0, 0, 0);
        }
    }

    float asv[4], adv[4];
#pragma unroll
    for (int nt = 0; nt < 4; ++nt) {
        asv[nt] = a_src[nt * 16 + lm];
        adv[nt] = a_dst[nt * 16 + lm];
    }
#pragma unroll
    for (int mt = 0; mt < 2; ++mt) {
#pragma unroll
        for (int r = 0; r < 4; ++r) {
            float s0 = 0.f, d0 = 0.f;
#pragma unroll
            for (int nt = 0; nt < 4; ++nt) {
                s0 += acc[mt][nt][r] * asv[nt];
                d0 += acc[mt][nt][r] * adv[nt];
            }
#pragma unroll
            for (int m = 1; m < 16; m <<= 1) {
                s0 += __shfl_xor(s0, m, 64);
                d0 += __shfl_xor(d0, m, 64);
            }
            if (lm == 0) {
                int gr = r0 + wv * 32 + mt * 16 + quad * 4 + r;
                if (gr < N_NODES) {
                    as_out[gr] = s0;
                    ad_out[gr] = d0;
                }
            }
        }
    }

    __syncthreads();
#pragma unroll
    for (int mt = 0; mt < 2; ++mt) {
#pragma unroll
        for (int nt = 0; nt < 4; ++nt) {
#pragma unroll
            for (int r = 0; r < 4; ++r) {
                int lrow = wv * 32 + mt * 16 + quad * 4 + r;
                wt[swz64(lrow, nt * 16 + lm)] = f2bf(acc[mt][nt][r]);
            }
        }
    }
    __syncthreads();
    {
        int lrow = tid >> 1;
        int cb = (tid & 1) * 32;
        int gr = r0 + lrow;
        if (gr < N_NODES) {
            unsigned short* dst = h2b + (size_t)gr * 64 + cb;
#pragma unroll
            for (int c = 0; c < 4; ++c)
                *(uint4*)(dst + c * 8) = *(uint4*)&wt[swz64(lrow, cb + c * 8)];
        }
    }
}

// -------- layer 2 aggregate: half-wave/edge, 8 edges per iteration (ushort csr) --------
__global__ void agg2_kernel(const unsigned short* __restrict__ h2b,
                            const float* __restrict__ as2,
                            const float* __restrict__ ad2, const float* __restrict__ b2,
                            const int* __restrict__ offsets, const int* __restrict__ deg,
                            const unsigned short* __restrict__ csr_us,
                            float* __restrict__ out) {
    int wid = (blockIdx.x * blockDim.x + threadIdx.x) >> 6;
    if (wid >= N_NODES) return;
    int lane = threadIdx.x & 63;
    int cl = lane & 31;
    int half = lane >> 5;
    float da = ad2[wid];
    int jb = offsets[wid], je = jb + deg[wid];
    float acc0 = 0.f, acc1 = 0.f, psum = 0.f;

    for (int chunk = jb; chunk < je; chunk += 64) {
        int j = chunk + lane;
        int s = 0; float w = 0.f;
        if (j < je) {
            s = (int)csr_us[j];
            w = __expf(lrelu(as2[s] + da));
        }
        psum += w;
        int cnt = je - chunk; if (cnt > 64) cnt = 64;
        for (int k = 0; k < cnt; k += 8) {
            int k0 = k + half, k1 = k + 2 + half, k2 = k + 4 + half, k3 = k + 6 + half;
            int ss0 = __shfl(s, k0, 64);
            int ss1 = __shfl(s, k1, 64);
            int ss2 = __shfl(s, k2, 64);
            int ss3 = __shfl(s, k3, 64);
            unsigned u0 = ((const unsigned*)(h2b + (size_t)ss0 * 64))[cl];
            unsigned u1 = ((const unsigned*)(h2b + (size_t)ss1 * 64))[cl];
            unsigned u2 = ((const unsigned*)(h2b + (size_t)ss2 * 64))[cl];
            unsigned u3 = ((const unsigned*)(h2b + (size_t)ss3 * 64))[cl];
            float bw0 = __shfl(w, k0, 64);
            float bw1 = __shfl(w, k1, 64);
            float bw2 = __shfl(w, k2, 64);
            float bw3 = __shfl(w, k3, 64);
            acc0 += bw0 * bflo(u0); acc1 += bw0 * bfhi(u0);
            acc0 += bw1 * bflo(u1); acc1 += bw1 * bfhi(u1);
            acc0 += bw2 * bflo(u2); acc1 += bw2 * bfhi(u2);
            acc0 += bw3 * bflo(u3); acc1 += bw3 * bfhi(u3);
        }
    }
#pragma unroll
    for (int m = 1; m < 64; m <<= 1) psum += __shfl_xor(psum, m, 64);
    float o0 = __shfl(acc0, cl + 32, 64);
    float o1 = __shfl(acc1, cl + 32, 64);
    if (lane < 32) {
        float inv = 1.f / psum;
        float2 bv = *(const float2*)&b2[cl * 2];
        float v0 = (acc0 + o0) * inv + bv.x;
        float v1 = (acc1 + o1) * inv + bv.y;
        v0 = 1.f / (1.f + __expf(-v0));
        v1 = 1.f / (1.f + __expf(-v1));
        *(float2*)&out[(size_t)wid * 64 + cl * 2] = make_float2(v0, v1);
    }
}

extern "C" void kernel_launch(void* const* d_in, const int* in_sizes, int n_in,
                              void* d_out, int out_size, void* d_ws, size_t ws_size,
                              hipStream_t stream) {
    const float* x     = (const float*)d_in[0];
    const int*   ei    = (const int*)d_in[1];
    const float* W1    = (const float*)d_in[2];
    const float* asrc1 = (const float*)d_in[3];
    const float* adst1 = (const float*)d_in[4];
    const float* b1    = (const float*)d_in[5];
    const float* W2    = (const float*)d_in[6];
    const float* asrc2 = (const float*)d_in[7];
    const float* adst2 = (const float*)d_in[8];
    const float* b2    = (const float*)d_in[9];
    float* out = (float*)d_out;

    float* ws = (float*)d_ws;
    size_t off = 0;
    float* as1  = ws + off; off += (size_t)N_NODES * 2;
    float* ad1  = ws + off; off += (size_t)N_NODES * 2;
    float* as2  = ws + off; off += (size_t)N_NODES;
    float* ad2  = ws + off; off += (size_t)N_NODES;
    unsigned short* h1b   = (unsigned short*)(ws + off); off += (size_t)N_NODES * 64;  // 128 bf16
    unsigned short* out1b = (unsigned short*)(ws + off); off += (size_t)N_NODES * 64;  // 128 bf16
    unsigned short* h2b   = (unsigned short*)(ws + off); off += (size_t)N_NODES * 32;  // 64 bf16
    int* offsets = (int*)(ws + off); off += N_NODES;
    int* deg     = (int*)(ws + off); off += N_NODES;
    unsigned short* csr_us = (unsigned short*)(ws + off);
    off += ((size_t)NB_BKT * BKT_CAP + 1) / 2;            // ushort csr, padded
    int* bktcnt  = (int*)(ws + off); off += NB_BKT;
    uint2* pairs = (uint2*)((((size_t)(ws + off)) + 7) & ~(size_t)7);

    hipMemsetAsync(bktcnt, 0, NB_BKT * sizeof(int), stream);

    fusedA_kernel<<<NB_G1 + NB_P1, 256, 0, stream>>>(x, W1, asrc1, adst1, h1b, as1, ad1,
                                                     ei, bktcnt, pairs);
    agg1_kernel<<<NB_BKT, 1024, 0, stream>>>(h1b, as1, ad1, b1, pairs, bktcnt,
                                             offsets, deg, csr_us, out1b);
    gemm2_kernel<<<NB_G1, 256, 0, stream>>>(out1b, W2, asrc2, adst2, h2b, as2, ad2);
    agg2_kernel<<<(N_NODES * 64 + 255) / 256, 256, 0, stream>>>(h2b, as2, ad2, b2, offsets, deg, csr_us, out);
}

// Round 12
// 196.309 us; speedup vs baseline: 1.0031x; 1.0031x over previous
//
#include <hip/hip_runtime.h>
#include <math.h>

#define N_NODES 50000
#define N_EDGES 800000
#define E_TOT   (N_EDGES + N_NODES)
#define NEG_SLOPE 0.2f
#define NB_BKT  ((N_NODES + 255) / 256)   // 196 dst-buckets of 256 nodes
#define BKT_CAP 5632                      // mean 4352 + 20 sigma (uniform dst)
#define P1_CHUNK 4096
#define NB_P1   ((E_TOT + P1_CHUNK - 1) / P1_CHUNK)   // 208 scatter blocks
#define NB_G1   ((N_NODES + 127) / 128)   // 391 gemm blocks

typedef short bf16x8 __attribute__((ext_vector_type(8)));
typedef float f32x4 __attribute__((ext_vector_type(4)));

static __device__ __forceinline__ float lrelu(float v) {
    return v > 0.0f ? v : NEG_SLOPE * v;
}

// round-to-nearest-even fp32 -> bf16
static __device__ __forceinline__ unsigned short f2bf(float f) {
    unsigned b = __float_as_uint(f);
    return (unsigned short)((b + 0x7fffu + ((b >> 16) & 1u)) >> 16);
}

static __device__ __forceinline__ float bflo(unsigned u) { return __uint_as_float(u << 16); }
static __device__ __forceinline__ float bfhi(unsigned u) { return __uint_as_float(u & 0xffff0000u); }

// LDS index (ushort units) for element (row, k) of a row*128 bf16 tile.
static __device__ __forceinline__ int swz(int row, int k) {
    return row * 128 + ((((k >> 3) ^ (row & 15)) << 3) | (k & 7));
}
static __device__ __forceinline__ int swz64(int row, int c) {
    return row * 64 + ((((c >> 3) ^ (row & 7)) << 3) | (c & 7));
}

// -------- fused A: blocks [0,NB_G1) = GEMM1 (bf16 MFMA) + alphas1;
//                   blocks [NB_G1, NB_G1+NB_P1) = bucket-binned edge scatter.
// pairs entry: (dst&255)<<16 | src   (src < 65536, dst-local 8 bits)
__global__ __launch_bounds__(256, 2) void fusedA_kernel(const float* __restrict__ x,
                                                        const float* __restrict__ W,
                                                        const float* __restrict__ a_src,
                                                        const float* __restrict__ a_dst,
                                                        unsigned short* __restrict__ h1b,
                                                        float* __restrict__ as_out,
                                                        float* __restrict__ ad_out,
                                                        const int* __restrict__ ei,
                                                        int* __restrict__ bktcnt,
                                                        unsigned* __restrict__ pairs) {
    __shared__ __align__(16) unsigned char smem[65536];
    int tid = threadIdx.x;

    if (blockIdx.x >= NB_G1) {
        // ---------------- scatter P1 path ----------------
        int* cnt  = (int*)smem;
        int* base = (int*)(smem + 1024);
        for (int i = tid; i < NB_BKT; i += 256) cnt[i] = 0;
        __syncthreads();
        int cbase = (blockIdx.x - NB_G1) * P1_CHUNK;
        for (int i = tid; i < P1_CHUNK; i += 256) {
            int e = cbase + i;
            if (e >= E_TOT) break;
            int d = (e < N_EDGES) ? ei[N_EDGES + e] : (e - N_EDGES);
            atomicAdd(&cnt[d >> 8], 1);
        }
        __syncthreads();
        for (int i = tid; i < NB_BKT; i += 256) {
            int c = cnt[i];
            base[i] = c ? (BKT_CAP * i + atomicAdd(&bktcnt[i], c)) : 0;
            cnt[i] = 0;
        }
        __syncthreads();
        for (int i = tid; i < P1_CHUNK; i += 256) {
            int e = cbase + i;
            if (e >= E_TOT) break;
            int s, d;
            if (e < N_EDGES) { s = ei[e]; d = ei[N_EDGES + e]; }
            else { s = d = e - N_EDGES; }
            int bk = d >> 8;
            int p = base[bk] + atomicAdd(&cnt[bk], 1);
            pairs[p] = ((unsigned)(d & 255) << 16) | (unsigned)s;
        }
        return;
    }

    // ---------------- GEMM1 path ----------------
    unsigned short* xs = (unsigned short*)smem;            // 32 KB
    unsigned short* wt = (unsigned short*)(smem + 32768);  // 32 KB, W^T
    int r0 = blockIdx.x * 128;

    {   // stage W^T
        int n = tid & 127;
        int c0 = (tid >> 7) * 8;
        for (int c = c0; c < c0 + 8; ++c) {
            int kb = c * 8;
            ushort4 lo, hi;
            lo.x = f2bf(W[(kb + 0) * 128 + n]);
            lo.y = f2bf(W[(kb + 1) * 128 + n]);
            lo.z = f2bf(W[(kb + 2) * 128 + n]);
            lo.w = f2bf(W[(kb + 3) * 128 + n]);
            hi.x = f2bf(W[(kb + 4) * 128 + n]);
            hi.y = f2bf(W[(kb + 5) * 128 + n]);
            hi.z = f2bf(W[(kb + 6) * 128 + n]);
            hi.w = f2bf(W[(kb + 7) * 128 + n]);
            int a = swz(n, kb);
            *(ushort4*)&wt[a] = lo;
            *(ushort4*)&wt[a + 4] = hi;
        }
    }
    {   // stage x rows as bf16
        const int maxe = N_NODES * 128 - 4;
#pragma unroll
        for (int i = 0; i < 16384; i += 1024) {
            int e = i + tid * 4;
            int ge = r0 * 128 + e;
            if (ge > maxe) ge = maxe;
            float4 v = *(const float4*)&x[ge];
            ushort4 p;
            p.x = f2bf(v.x); p.y = f2bf(v.y); p.z = f2bf(v.z); p.w = f2bf(v.w);
            *(ushort4*)&xs[swz(e >> 7, e & 127)] = p;
        }
    }
    __syncthreads();

    int wv = tid >> 6, lane = tid & 63, lm = lane & 15, quad = lane >> 4;
    f32x4 acc[2][8];
#pragma unroll
    for (int m = 0; m < 2; ++m)
#pragma unroll
        for (int n = 0; n < 8; ++n) acc[m][n] = (f32x4){0.f, 0.f, 0.f, 0.f};

#pragma unroll
    for (int kc = 0; kc < 4; ++kc) {
        int kb = kc * 32 + quad * 8;
        bf16x8 a0 = *(bf16x8*)&xs[swz(wv * 32 + lm, kb)];
        bf16x8 a1 = *(bf16x8*)&xs[swz(wv * 32 + 16 + lm, kb)];
#pragma unroll
        for (int nt = 0; nt < 8; ++nt) {
            bf16x8 b = *(bf16x8*)&wt[swz(nt * 16 + lm, kb)];
            acc[0][nt] = __builtin_amdgcn_mfma_f32_16x16x32_bf16(a0, b, acc[0][nt], 0, 0, 0);
            acc[1][nt] = __builtin_amdgcn_mfma_f32_16x16x32_bf16(a1, b, acc[1][nt], 0, 0, 0);
        }
    }

    float asv[8], adv[8];
#pragma unroll
    for (int nt = 0; nt < 8; ++nt) {
        asv[nt] = a_src[nt * 16 + lm];
        adv[nt] = a_dst[nt * 16 + lm];
    }
#pragma unroll
    for (int mt = 0; mt < 2; ++mt) {
#pragma unroll
        for (int r = 0; r < 4; ++r) {
            float s0 = 0.f, s1 = 0.f, d0 = 0.f, d1 = 0.f;
#pragma unroll
            for (int nt = 0; nt < 4; ++nt) {
                s0 += acc[mt][nt][r] * asv[nt];
                d0 += acc[mt][nt][r] * adv[nt];
            }
#pragma unroll
            for (int nt = 4; nt < 8; ++nt) {
                s1 += acc[mt][nt][r] * asv[nt];
                d1 += acc[mt][nt][r] * adv[nt];
            }
#pragma unroll
            for (int m = 1; m < 16; m <<= 1) {
                s0 += __shfl_xor(s0, m, 64);
                s1 += __shfl_xor(s1, m, 64);
                d0 += __shfl_xor(d0, m, 64);
                d1 += __shfl_xor(d1, m, 64);
            }
            if (lm == 0) {
                int gr = r0 + wv * 32 + mt * 16 + quad * 4 + r;
                if (gr < N_NODES) {
                    as_out[gr * 2 + 0] = s0;
                    as_out[gr * 2 + 1] = s1;
                    ad_out[gr * 2 + 0] = d0;
                    ad_out[gr * 2 + 1] = d1;
                }
            }
        }
    }

    __syncthreads();
#pragma unroll
    for (int mt = 0; mt < 2; ++mt) {
#pragma unroll
        for (int nt = 0; nt < 8; ++nt) {
#pragma unroll
            for (int r = 0; r < 4; ++r) {
                int lrow = wv * 32 + mt * 16 + quad * 4 + r;
                xs[swz(lrow, nt * 16 + lm)] = f2bf(acc[mt][nt][r]);
            }
        }
    }
    __syncthreads();
    {
        int lrow = tid >> 1;
        int cb = (tid & 1) * 64;
        int gr = r0 + lrow;
        if (gr < N_NODES) {
            unsigned short* dst = h1b + (size_t)gr * 128 + cb;
#pragma unroll
            for (int c = 0; c < 8; ++c)
                *(uint4*)(dst + c * 8) = *(uint4*)&xs[swz(lrow, cb + c * 8)];
        }
    }
}

// -------- CSR build pass 2: per-bucket node scan + place (packed pairs, ushort csr) --------
__global__ void scatterP2_kernel(const unsigned* __restrict__ pairs, const int* __restrict__ bktcnt,
                                 int* __restrict__ offsets, int* __restrict__ deg,
                                 unsigned short* __restrict__ csr_us) {
    __shared__ int cnt[256];
    __shared__ int scn[256];
    int t = threadIdx.x;
    int b = blockIdx.x;
    int pbase = b * BKT_CAP;
    int node0 = b << 8;
    int cntE = bktcnt[b];
    cnt[t] = 0;
    __syncthreads();
    for (int j = t; j < cntE; j += 256)
        atomicAdd(&cnt[pairs[pbase + j] >> 16], 1);
    __syncthreads();
    int v = cnt[t];
    scn[t] = v;
    __syncthreads();
#pragma unroll
    for (int off = 1; off < 256; off <<= 1) {
        int u = (t >= off) ? scn[t - off] : 0;
        __syncthreads();
        scn[t] += u;
        __syncthreads();
    }
    int start = pbase + scn[t] - v;
    if (node0 + t < N_NODES) {
        offsets[node0 + t] = start;
        deg[node0 + t] = v;
    }
    cnt[t] = start;
    __syncthreads();
    for (int j = t; j < cntE; j += 256) {
        unsigned pk = pairs[pbase + j];
        int p = atomicAdd(&cnt[pk >> 16], 1);
        csr_us[p] = (unsigned short)(pk & 0xFFFFu);
    }
}

// -------- GEMM 2 (bf16 MFMA) + fused alphas2: h2b[N,64], as2/ad2[N] --------
__global__ __launch_bounds__(256, 2) void gemm2_kernel(const unsigned short* __restrict__ xb,
                                                       const float* __restrict__ W,
                                                       const float* __restrict__ a_src,
                                                       const float* __restrict__ a_dst,
                                                       unsigned short* __restrict__ h2b,
                                                       float* __restrict__ as_out,
                                                       float* __restrict__ ad_out) {
    __shared__ unsigned short xs[128 * 128];  // 32 KB
    __shared__ unsigned short wt[64 * 128];   // 16 KB, W^T
    int tid = threadIdx.x;
    int r0 = blockIdx.x * 128;

    {
        int n = tid & 63;
        int c0 = (tid >> 6) * 4;
        for (int c = c0; c < c0 + 4; ++c) {
            int kb = c * 8;
            ushort4 lo, hi;
            lo.x = f2bf(W[(kb + 0) * 64 + n]);
            lo.y = f2bf(W[(kb + 1) * 64 + n]);
            lo.z = f2bf(W[(kb + 2) * 64 + n]);
            lo.w = f2bf(W[(kb + 3) * 64 + n]);
            hi.x = f2bf(W[(kb + 4) * 64 + n]);
            hi.y = f2bf(W[(kb + 5) * 64 + n]);
            hi.z = f2bf(W[(kb + 6) * 64 + n]);
            hi.w = f2bf(W[(kb + 7) * 64 + n]);
            int a = swz(n, kb);
            *(ushort4*)&wt[a] = lo;
            *(ushort4*)&wt[a + 4] = hi;
        }
    }
    {
        const int maxe = N_NODES * 128 - 8;
#pragma unroll
        for (int i = 0; i < 16384; i += 2048) {
            int e = i + tid * 8;
            int ge = r0 * 128 + e;
            if (ge > maxe) ge = maxe;
            uint4 v = *(const uint4*)&xb[ge];
            *(uint4*)&xs[swz(e >> 7, e & 127)] = v;
        }
    }
    __syncthreads();

    int wv = tid >> 6, lane = tid & 63, lm = lane & 15, quad = lane >> 4;
    f32x4 acc[2][4];
#pragma unroll
    for (int m = 0; m < 2; ++m)
#pragma unroll
        for (int n = 0; n < 4; ++n) acc[m][n] = (f32x4){0.f, 0.f, 0.f, 0.f};

#pragma unroll
    for (int kc = 0; kc < 4; ++kc) {
        int kb = kc * 32 + quad * 8;
        bf16x8 a0 = *(bf16x8*)&xs[swz(wv * 32 + lm, kb)];
        bf16x8 a1 = *(bf16x8*)&xs[swz(wv * 32 + 16 + lm, kb)];
#pragma unroll
        for (int nt = 0; nt < 4; ++nt) {
            bf16x8 b = *(bf16x8*)&wt[swz(nt * 16 + lm, kb)];
            acc[0][nt] = __builtin_amdgcn_mfma_f32_16x16x32_bf16(a0, b, acc[0][nt], 0, 0, 0);
            acc[1][nt] = __builtin_amdgcn_mfma_f32_16x16x32_bf16(a1, b, acc[1][nt], 0, 0, 0);
        }
    }

    float asv[4], adv[4];
#pragma unroll
    for (int nt = 0; nt < 4; ++nt) {
        asv[nt] = a_src[nt * 16 + lm];
        adv[nt] = a_dst[nt * 16 + lm];
    }
#pragma unroll
    for (int mt = 0; mt < 2; ++mt) {
#pragma unroll
        for (int r = 0; r < 4; ++r) {
            float s0 = 0.f, d0 = 0.f;
#pragma unroll
            for (int nt = 0; nt < 4; ++nt) {
                s0 += acc[mt][nt][r] * asv[nt];
                d0 += acc[mt][nt][r] * adv[nt];
            }
#pragma unroll
            for (int m = 1; m < 16; m <<= 1) {
                s0 += __shfl_xor(s0, m, 64);
                d0 += __shfl_xor(d0, m, 64);
            }
            if (lm == 0) {
                int gr = r0 + wv * 32 + mt * 16 + quad * 4 + r;
                if (gr < N_NODES) {
                    as_out[gr] = s0;
                    ad_out[gr] = d0;
                }
            }
        }
    }

    __syncthreads();
#pragma unroll
    for (int mt = 0; mt < 2; ++mt) {
#pragma unroll
        for (int nt = 0; nt < 4; ++nt) {
#pragma unroll
            for (int r = 0; r < 4; ++r) {
                int lrow = wv * 32 + mt * 16 + quad * 4 + r;
                wt[swz64(lrow, nt * 16 + lm)] = f2bf(acc[mt][nt][r]);
            }
        }
    }
    __syncthreads();
    {
        int lrow = tid >> 1;
        int cb = (tid & 1) * 32;
        int gr = r0 + lrow;
        if (gr < N_NODES) {
            unsigned short* dst = h2b + (size_t)gr * 64 + cb;
#pragma unroll
            for (int c = 0; c < 4; ++c)
                *(uint4*)(dst + c * 8) = *(uint4*)&wt[swz64(lrow, cb + c * 8)];
        }
    }
}

// -------- layer 1 aggregate: half-wave/edge, uint2 gather, 8 edges/iter (ushort csr) --------
__global__ void agg1_kernel(const unsigned short* __restrict__ h1b,
                            const float* __restrict__ as1,
                            const float* __restrict__ ad1, const float* __restrict__ b1,
                            const int* __restrict__ offsets, const int* __restrict__ deg,
                            const unsigned short* __restrict__ csr_us,
                            unsigned short* __restrict__ out1b) {
    int wid = (blockIdx.x * blockDim.x + threadIdx.x) >> 6;
    if (wid >= N_NODES) return;
    int lane = threadIdx.x & 63;
    int cl = lane & 31;
    int half = lane >> 5;
    bool head1 = (cl >= 16);
    float da0 = ad1[wid * 2 + 0], da1 = ad1[wid * 2 + 1];
    int jb = offsets[wid], je = jb + deg[wid];
    float a0 = 0.f, a1 = 0.f, a2 = 0.f, a3 = 0.f;
    float psum0 = 0.f, psum1 = 0.f;

    for (int chunk = jb; chunk < je; chunk += 64) {
        int j = chunk + lane;
        int s = 0; float w0 = 0.f, w1 = 0.f;
        if (j < je) {
            s = (int)csr_us[j];
            float2 av = *(const float2*)&as1[s * 2];
            w0 = __expf(lrelu(av.x + da0));
            w1 = __expf(lrelu(av.y + da1));
        }
        psum0 += w0; psum1 += w1;
        int cnt = je - chunk; if (cnt > 64) cnt = 64;
        for (int k = 0; k < cnt; k += 8) {
            int k0 = k + half, k1 = k + 2 + half, k2 = k + 4 + half, k3 = k + 6 + half;
            int ss0 = __shfl(s, k0, 64);
            int ss1 = __shfl(s, k1, 64);
            int ss2 = __shfl(s, k2, 64);
            int ss3 = __shfl(s, k3, 64);
            uint2 u0 = ((const uint2*)(h1b + (size_t)ss0 * 128))[cl];
            uint2 u1 = ((const uint2*)(h1b + (size_t)ss1 * 128))[cl];
            uint2 u2 = ((const uint2*)(h1b + (size_t)ss2 * 128))[cl];
            uint2 u3 = ((const uint2*)(h1b + (size_t)ss3 * 128))[cl];
            float p0 = __shfl(w0, k0, 64), q0 = __shfl(w1, k0, 64);
            float p1 = __shfl(w0, k1, 64), q1 = __shfl(w1, k1, 64);
            float p2 = __shfl(w0, k2, 64), q2 = __shfl(w1, k2, 64);
            float p3 = __shfl(w0, k3, 64), q3 = __shfl(w1, k3, 64);
            float bw0 = head1 ? q0 : p0;
            float bw1 = head1 ? q1 : p1;
            float bw2 = head1 ? q2 : p2;
            float bw3 = head1 ? q3 : p3;
            a0 += bw0 * bflo(u0.x); a1 += bw0 * bfhi(u0.x); a2 += bw0 * bflo(u0.y); a3 += bw0 * bfhi(u0.y);
            a0 += bw1 * bflo(u1.x); a1 += bw1 * bfhi(u1.x); a2 += bw1 * bflo(u1.y); a3 += bw1 * bfhi(u1.y);
            a0 += bw2 * bflo(u2.x); a1 += bw2 * bfhi(u2.x); a2 += bw2 * bflo(u2.y); a3 += bw2 * bfhi(u2.y);
            a0 += bw3 * bflo(u3.x); a1 += bw3 * bfhi(u3.x); a2 += bw3 * bflo(u3.y); a3 += bw3 * bfhi(u3.y);
        }
    }
#pragma unroll
    for (int m = 1; m < 64; m <<= 1) {
        psum0 += __shfl_xor(psum0, m, 64);
        psum1 += __shfl_xor(psum1, m, 64);
    }
    float o0 = __shfl(a0, cl + 32, 64);
    float o1 = __shfl(a1, cl + 32, 64);
    float o2 = __shfl(a2, cl + 32, 64);
    float o3 = __shfl(a3, cl + 32, 64);
    if (lane < 32) {
        float inv = 1.f / (head1 ? psum1 : psum0);
        float4 bv = *(const float4*)&b1[cl * 4];
        float v0 = (a0 + o0) * inv + bv.x;
        float v1 = (a1 + o1) * inv + bv.y;
        float v2 = (a2 + o2) * inv + bv.z;
        float v3 = (a3 + o3) * inv + bv.w;
        v0 = v0 > 0.f ? v0 : 0.f;
        v1 = v1 > 0.f ? v1 : 0.f;
        v2 = v2 > 0.f ? v2 : 0.f;
        v3 = v3 > 0.f ? v3 : 0.f;
        ushort4 p;
        p.x = f2bf(v0); p.y = f2bf(v1); p.z = f2bf(v2); p.w = f2bf(v3);
        *(ushort4*)&out1b[(size_t)wid * 128 + cl * 4] = p;
    }
}

// -------- layer 2 aggregate: half-wave/edge, 8 edges per iteration (ushort csr) --------
__global__ void agg2_kernel(const unsigned short* __restrict__ h2b,
                            const float* __restrict__ as2,
                            const float* __restrict__ ad2, const float* __restrict__ b2,
                            const int* __restrict__ offsets, const int* __restrict__ deg,
                            const unsigned short* __restrict__ csr_us,
                            float* __restrict__ out) {
    int wid = (blockIdx.x * blockDim.x + threadIdx.x) >> 6;
    if (wid >= N_NODES) return;
    int lane = threadIdx.x & 63;
    int cl = lane & 31;
    int half = lane >> 5;
    float da = ad2[wid];
    int jb = offsets[wid], je = jb + deg[wid];
    float acc0 = 0.f, acc1 = 0.f, psum = 0.f;

    for (int chunk = jb; chunk < je; chunk += 64) {
        int j = chunk + lane;
        int s = 0; float w = 0.f;
        if (j < je) {
            s = (int)csr_us[j];
            w = __expf(lrelu(as2[s] + da));
        }
        psum += w;
        int cnt = je - chunk; if (cnt > 64) cnt = 64;
        for (int k = 0; k < cnt; k += 8) {
            int k0 = k + half, k1 = k + 2 + half, k2 = k + 4 + half, k3 = k + 6 + half;
            int ss0 = __shfl(s, k0, 64);
            int ss1 = __shfl(s, k1, 64);
            int ss2 = __shfl(s, k2, 64);
            int ss3 = __shfl(s, k3, 64);
            unsigned u0 = ((const unsigned*)(h2b + (size_t)ss0 * 64))[cl];
            unsigned u1 = ((const unsigned*)(h2b + (size_t)ss1 * 64))[cl];
            unsigned u2 = ((const unsigned*)(h2b + (size_t)ss2 * 64))[cl];
            unsigned u3 = ((const unsigned*)(h2b + (size_t)ss3 * 64))[cl];
            float bw0 = __shfl(w, k0, 64);
            float bw1 = __shfl(w, k1, 64);
            float bw2 = __shfl(w, k2, 64);
            float bw3 = __shfl(w, k3, 64);
            acc0 += bw0 * bflo(u0); acc1 += bw0 * bfhi(u0);
            acc0 += bw1 * bflo(u1); acc1 += bw1 * bfhi(u1);
            acc0 += bw2 * bflo(u2); acc1 += bw2 * bfhi(u2);
            acc0 += bw3 * bflo(u3); acc1 += bw3 * bfhi(u3);
        }
    }
#pragma unroll
    for (int m = 1; m < 64; m <<= 1) psum += __shfl_xor(psum, m, 64);
    float o0 = __shfl(acc0, cl + 32, 64);
    float o1 = __shfl(acc1, cl + 32, 64);
    if (lane < 32) {
        float inv = 1.f / psum;
        float2 bv = *(const float2*)&b2[cl * 2];
        float v0 = (acc0 + o0) * inv + bv.x;
        float v1 = (acc1 + o1) * inv + bv.y;
        v0 = 1.f / (1.f + __expf(-v0));
        v1 = 1.f / (1.f + __expf(-v1));
        *(float2*)&out[(size_t)wid * 64 + cl * 2] = make_float2(v0, v1);
    }
}

extern "C" void kernel_launch(void* const* d_in, const int* in_sizes, int n_in,
                              void* d_out, int out_size, void* d_ws, size_t ws_size,
                              hipStream_t stream) {
    const float* x     = (const float*)d_in[0];
    const int*   ei    = (const int*)d_in[1];
    const float* W1    = (const float*)d_in[2];
    const float* asrc1 = (const float*)d_in[3];
    const float* adst1 = (const float*)d_in[4];
    const float* b1    = (const float*)d_in[5];
    const float* W2    = (const float*)d_in[6];
    const float* asrc2 = (const float*)d_in[7];
    const float* adst2 = (const float*)d_in[8];
    const float* b2    = (const float*)d_in[9];
    float* out = (float*)d_out;

    float* ws = (float*)d_ws;
    size_t off = 0;
    float* as1  = ws + off; off += (size_t)N_NODES * 2;
    float* ad1  = ws + off; off += (size_t)N_NODES * 2;
    float* as2  = ws + off; off += (size_t)N_NODES;
    float* ad2  = ws + off; off += (size_t)N_NODES;
    unsigned short* h1b   = (unsigned short*)(ws + off); off += (size_t)N_NODES * 64;  // 128 bf16
    unsigned short* out1b = (unsigned short*)(ws + off); off += (size_t)N_NODES * 64;  // 128 bf16
    unsigned short* h2b   = (unsigned short*)(ws + off); off += (size_t)N_NODES * 32;  // 64 bf16
    int* offsets = (int*)(ws + off); off += N_NODES;
    int* deg     = (int*)(ws + off); off += N_NODES;
    unsigned short* csr_us = (unsigned short*)(ws + off);
    off += ((size_t)NB_BKT * BKT_CAP + 1) / 2;            // ushort csr (padded layout)
    int* bktcnt  = (int*)(ws + off); off += NB_BKT;
    unsigned* pairs = (unsigned*)(ws + off);              // packed 4B pairs

    hipMemsetAsync(bktcnt, 0, NB_BKT * sizeof(int), stream);

    fusedA_kernel<<<NB_G1 + NB_P1, 256, 0, stream>>>(x, W1, asrc1, adst1, h1b, as1, ad1,
                                                     ei, bktcnt, pairs);
    scatterP2_kernel<<<NB_BKT, 256, 0, stream>>>(pairs, bktcnt, offsets, deg, csr_us);
    agg1_kernel<<<(N_NODES * 64 + 255) / 256, 256, 0, stream>>>(h1b, as1, ad1, b1, offsets, deg, csr_us, out1b);
    gemm2_kernel<<<NB_G1, 256, 0, stream>>>(out1b, W2, asrc2, adst2, h2b, as2, ad2);
    agg2_kernel<<<(N_NODES * 64 + 255) / 256, 256, 0, stream>>>(h2b, as2, ad2, b2, offsets, deg, csr_us, out);
}